// Round 6
// baseline (273.163 us; speedup 1.0000x reference)
//
#include <hip/hip_runtime.h>
#include <stdint.h>

// Problem constants
#define NJ 192                    // N1
#define OUT_HALF 12582912         // B*HN*N1 = 4096*16*192

// LDS geometry
#define XS 520      // X: 64 x 520 bf16 (interleaved rgb/tir: col 2k=rgb_k, 2k+1=tir_k)
#define OSD 516     // O: 32 x 516 f32 per row-half pass (stride 2064B, bank shift 4)

// Arena byte layout (67584 total -> 2 blocks/CU), phases strictly sequential:
//   sX    [0, 66560)        64x520 bf16; live through GEMM1 (A read per chunk)
//   sH    [32768, 65536)    64x256 bf16 swizzled; overlays sX AFTER GEMM1 barrier
//   sStat [67072, 67584)    64 x {rs, mu*rs} f32 (outside sX/sO; scatter -> epi1)
//   sO    [0, 66048)        32x516 f32; overlays everything AFTER GEMM2 barrier
// NO weight slots: B-fragments stream global(L2) -> VGPR directly; K-loops
// have ZERO barriers / ZERO inline-asm waitcnt (compiler tracks reg loads).
#define H_BYTE 32768
#define STAT_OFF 67072
#define ARENA  67584

typedef __attribute__((ext_vector_type(4)))  float    f32x4;
typedef __attribute__((ext_vector_type(16))) float    f32x16;
typedef __attribute__((ext_vector_type(2)))  float    f32x2;
typedef __attribute__((ext_vector_type(4)))  int      i32x4;
typedef __attribute__((ext_vector_type(4)))  uint32_t u32x4;
typedef __attribute__((ext_vector_type(8)))  short    bf16x8;

// u1[d] = b1[d] + sum_e W1[d][e]*ln_b[e];  v1[d] = sum_e W1[d][e]*ln_g[e]
__device__ float g_u1[256];
__device__ float g_v1[256];

__device__ __forceinline__ uint32_t cvt_pk_bf16(float lo, float hi) {
    uint32_t r;
    asm("v_cvt_pk_bf16_f32 %0, %1, %2" : "=v"(r) : "v"(lo), "v"(hi));
    return r;
}

// ---------------------------------------------------------------------------
// Pre-kernel (UNCHANGED from r5 — layouts reused for direct per-lane loads).
//  P1: 32 units (c=K32-chunk, h=tile parity) of 8KB; unit 2c+h holds 8
//      n-tiles nt=2*t2+h at offset t2*1024 + lane*16;
//      elems = W1g[nt*16+(l&15)][il K-cols c*32+(l>>4)*8 ..+7], W1g=W1*g.
//  P2 (32x32x16 B-frags): 32 units (k=K16-step, h=col-half) of 8KB;
//      unit 2k+h holds 8 col-tiles t=h*8+f at offset f*1024 + lane*16;
//      elems = B[k*16+(l>>5)*8+j][t*32+(l&31)], B[kk][n]=W2[orow(n)][kk],
//      n interleaved: orow = (n>>1) + (n&1)*256.
// ---------------------------------------------------------------------------
__global__ __launch_bounds__(256)
void pack_weights(const float* __restrict__ W1, const float* __restrict__ W2,
                  const float* __restrict__ ln_g, const float* __restrict__ ln_b,
                  const float* __restrict__ b1, short* __restrict__ ws) {
    if (blockIdx.x == 128) {            // u1 / v1 block
        int d = threadIdx.x;            // 0..255
        float u = b1[d], v = 0.f;
        const float* wr = W1 + d * 512;
        for (int e = 0; e < 512; e += 4) {
            f32x4 w4 = *(const f32x4*)(wr + e);
            f32x4 g4 = *(const f32x4*)(ln_g + e);
            f32x4 l4 = *(const f32x4*)(ln_b + e);
            #pragma unroll
            for (int t = 0; t < 4; ++t) { v += w4[t] * g4[t]; u += w4[t] * l4[t]; }
        }
        g_u1[d] = u; g_v1[d] = v;
        return;
    }
    int id = blockIdx.x * 256 + threadIdx.x;     // 0..32767
    if (id < 16384) {                   // P1
        int u8 = id >> 9, w = id & 511;
        int c = u8 >> 1, h = u8 & 1;
        int t2 = w >> 6, lane = w & 63;
        int nt = 2 * t2 + h;
        int row = nt * 16 + (lane & 15);
        int k0 = c * 16 + ((lane >> 4) << 2);     // orig rgb col base
        f32x4 a  = *(const f32x4*)(W1 + row * 512 + k0);
        f32x4 b  = *(const f32x4*)(W1 + row * 512 + 256 + k0);
        f32x4 ga = *(const f32x4*)(ln_g + k0);
        f32x4 gb = *(const f32x4*)(ln_g + 256 + k0);
        u32x4 o;
        #pragma unroll
        for (int t = 0; t < 4; ++t) o[t] = cvt_pk_bf16(a[t] * ga[t], b[t] * gb[t]);
        *(u32x4*)(ws + id * 8) = o;
    } else {                            // P2, 32x32x16 B layout
        int id2 = id - 16384;           // 0..16383
        int u = id2 >> 9;               // unit 0..31
        int g = id2 & 511;
        int f = g >> 6, lane = g & 63;
        int k = u >> 1, h = u & 1;
        int t = h * 8 + f;
        int n = t * 32 + (lane & 31);             // interleaved out col
        int orow = (n >> 1) + (n & 1) * 256;
        int k0 = k * 16 + ((lane >> 5) << 3);
        f32x4 a = *(const f32x4*)(W2 + orow * 256 + k0);
        f32x4 b = *(const f32x4*)(W2 + orow * 256 + k0 + 4);
        u32x4 o;
        o[0] = cvt_pk_bf16(a[0], a[1]);
        o[1] = cvt_pk_bf16(a[2], a[3]);
        o[2] = cvt_pk_bf16(b[0], b[1]);
        o[3] = cvt_pk_bf16(b[2], b[3]);
        *(u32x4*)(ws + 131072 + id2 * 8) = o;
    }
}

// ---------------------------------------------------------------------------
// Main kernel. 64 rows/block, 512 threads = 8 waves. GEMM1: 16x16x32,
// waves 4m x 2n, A from sX (1 ds_read/chunk, 2-way=free at XS=520), B direct
// global->VGPR. GEMM2: 32x32x16, waves 2m x 4n, A from swizzled sH, B direct
// global->VGPR. Zero barriers inside K-loops; waves fully decoupled.
// ---------------------------------------------------------------------------
__global__ __launch_bounds__(512, 4)
void fused_mlp(const float* __restrict__ rgb,
               const float* __restrict__ tir,
               const int*  __restrict__ gidx,
               const short* __restrict__ P1,
               const short* __restrict__ P2,
               const float* __restrict__ b2,
               float* __restrict__ out)
{
    __shared__ __attribute__((aligned(16))) char arena[ARENA];
    short* sX    = (short*)arena;
    short* sHsh  = (short*)(arena + H_BYTE);
    float* sStat = (float*)(arena + STAT_OFF);
    float* sO    = (float*)arena;

    const int tid  = threadIdx.x;
    const int blk  = blockIdx.x;
    const int row0 = blk * 64;
    const int b0   = blk * 4;
    const int wave = tid >> 6;
    const int lane = tid & 63;
    const int lr   = lane & 15;
    const int quad = lane >> 4;
    const int mw   = wave & 3;          // GEMM1 m-tile (16 rows)
    const int nw   = wave >> 2;         // GEMM1 n-half (8 n-tiles)
    const int mh   = wave >> 2;         // GEMM2 m-half (32 rows)
    const int nq   = wave & 3;          // GEMM2 n-quarter

    // ---- Phase 0: zero X data dwords ----
    {
        uint32_t* xd = (uint32_t*)sX;
        #pragma unroll
        for (int i = 0; i < 8; ++i) {
            int u = i * 512 + tid;
            int r = u >> 6, g = u & 63;
            *(u32x4*)(xd + r * 260 + g * 4) = (u32x4){0u, 0u, 0u, 0u};
        }
    }
    __syncthreads();

    // ---- Phase 1: fused scatter (raw bf16, rgb/tir interleaved) + LN stats ----
    {
        int r = tid >> 3, sub = tid & 7;
        int j0 = sub * 24;
        uint32_t* xdw = (uint32_t*)(sX + r * XS);
        const int*   gp = gidx + (b0 + (r >> 4)) * NJ + j0;
        const float* rp = rgb + (row0 + r) * NJ + j0;
        const float* tp = tir + (row0 + r) * NJ + j0;
        float s = 0.f, ss = 0.f;
        #pragma unroll
        for (int q = 0; q < 6; ++q) {
            i32x4 iv = *(const i32x4*)(gp + q * 4);
            f32x4 vr = *(const f32x4*)(rp + q * 4);
            f32x4 vt = *(const f32x4*)(tp + q * 4);
            #pragma unroll
            for (int e = 0; e < 4; ++e) {
                s  += vr[e] + vt[e];
                ss += vr[e] * vr[e] + vt[e] * vt[e];
                xdw[iv[e]] = cvt_pk_bf16(vr[e], vt[e]);
            }
        }
        s  += __shfl_xor(s, 1, 8);  ss += __shfl_xor(ss, 1, 8);
        s  += __shfl_xor(s, 2, 8);  ss += __shfl_xor(ss, 2, 8);
        s  += __shfl_xor(s, 4, 8);  ss += __shfl_xor(ss, 4, 8);
        float mu  = s * (1.f / 512.f);
        float var = ss * (1.f / 512.f) - mu * mu;
        float rs  = rsqrtf(var + 1e-5f);
        if (sub == 0) { sStat[2 * r] = rs; sStat[2 * r + 1] = mu * rs; }
    }
    __syncthreads();

    // ---- GEMM1: H(64x256) = X @ W1g^T, K=512 in 16 chunks of 32 ----
    // B-frag (tile nt = 8*nw + i, chunk c) at bytes:
    //   P1 + (2c + (i&1))*8192 + (nw*4 + (i>>1))*1024 + lane*16
    f32x4 acc1[8];
    #pragma unroll
    for (int i = 0; i < 8; ++i) acc1[i] = (f32x4){0.f, 0.f, 0.f, 0.f};

    {
        const short* xrow = sX + (mw * 16 + lr) * XS + quad * 8;
        const short* p1l  = P1 + ((nw * 4) << 9) + lane * 8;   // shorts
        #pragma unroll
        for (int c = 0; c < 16; ++c) {
            bf16x8 a = *(const bf16x8*)(xrow + c * 32);
            bf16x8 wf[8];
            #pragma unroll
            for (int i = 0; i < 8; ++i)
                wf[i] = *(const bf16x8*)(p1l + ((2 * c + (i & 1)) << 12) + ((i >> 1) << 9));
            #pragma unroll
            for (int i = 0; i < 8; ++i)
                acc1[i] = __builtin_amdgcn_mfma_f32_16x16x32_bf16(a, wf[i], acc1[i], 0, 0, 0);
        }
    }
    __syncthreads();    // ALL waves' sX reads done before sH overlays sX region

    // ---- Epilogue 1: h = rs*acc + (u1 - mu*rs*v1), relu -> swizzled bf16 H ----
    {
        const int baserow = mw * 16 + quad * 4;
        float rsv[4], mrs[4];
        #pragma unroll
        for (int rr = 0; rr < 4; ++rr) {
            rsv[rr] = sStat[2 * (baserow + rr)];
            mrs[rr] = sStat[2 * (baserow + rr) + 1];
        }
        #pragma unroll
        for (int i = 0; i < 8; ++i) {
            int col = (nw * 8 + i) * 16 + lr;
            int blkc = col >> 3, within = col & 7;
            float u1c = g_u1[col], v1c = g_v1[col];
            #pragma unroll
            for (int rr = 0; rr < 4; ++rr) {
                int r = baserow + rr;
                float hh = rsv[rr] * acc1[i][rr] + (u1c - mrs[rr] * v1c);
                hh = fmaxf(hh, 0.f);
                sHsh[r * 256 + ((blkc ^ (r & 31)) << 3) + within] = (short)cvt_pk_bf16(hh, hh);
            }
        }
    }
    __syncthreads();    // sH visible to all waves

    // ---- GEMM2: O'(64x512) = H @ W2'^T, K=256 in 16 steps of 16 ----
    // B-frag (tile t = (j>>1)*8 + nq*2 + (j&1), step k) at bytes:
    //   P2 + (2k + (t>>3))*8192 + (t&7)*1024 + lane*16
    f32x16 acc2[4];
    #pragma unroll
    for (int i = 0; i < 4; ++i)
        #pragma unroll
        for (int e = 0; e < 16; ++e) acc2[i][e] = 0.f;

    {
        const int r = mh * 32 + (lane & 31);
        const short* hrow = sHsh + r * 256;
        const short* p2l  = P2 + lane * 8;        // shorts
        #pragma unroll
        for (int k = 0; k < 16; ++k) {
            int blkc = (k * 2 + (lane >> 5)) ^ (r & 31);
            bf16x8 a2 = *(const bf16x8*)(hrow + blkc * 8);
            bf16x8 wf[4];
            #pragma unroll
            for (int j = 0; j < 4; ++j) {
                int t = (j >> 1) * 8 + nq * 2 + (j & 1);
                wf[j] = *(const bf16x8*)(p2l + ((2 * k + (t >> 3)) << 12) + ((t & 7) << 9));
            }
            #pragma unroll
            for (int j = 0; j < 4; ++j)
                acc2[j] = __builtin_amdgcn_mfma_f32_32x32x16_bf16(a2, wf[j], acc2[j], 0, 0, 0);
        }
    }
    __syncthreads();    // ALL waves' sH reads done before sO overlays them

    // ---- Epilogue 2 + gather: two 32-row passes through sO (32x516 f32) ----
    // 32x32 C/D layout: col = lane&31, row = (reg&3) + 8*(reg>>2) + 4*(lane>>5)
    #pragma unroll
    for (int p = 0; p < 2; ++p) {
        if (mh == p) {
            #pragma unroll
            for (int ai = 0; ai < 4; ++ai) {
                int t = (ai >> 1) * 8 + nq * 2 + (ai & 1);
                int colp = t * 32 + (lane & 31);
                float b2v = b2[(colp >> 1) + (colp & 1) * 256];
                #pragma unroll
                for (int rg = 0; rg < 16; ++rg) {
                    int lrow = (rg & 3) + 8 * (rg >> 2) + 4 * (lane >> 5);
                    float x = acc2[ai][rg] + b2v;
                    sO[lrow * OSD + colp] = 1.f / (1.f + __expf(-x));
                }
            }
        }
        __syncthreads();
        // gather rows p*32 .. p*32+31
        #pragma unroll
        for (int it = 0; it < 3; ++it) {
            int q4 = (it * 512 + tid) * 4;
            int rl = q4 / NJ;
            int jj = q4 - rl * NJ;
            int r  = p * 32 + rl;
            i32x4 iv = *(const i32x4*)(gidx + (b0 + (r >> 4)) * NJ + jj);
            const float* orow = sO + rl * OSD;
            f32x4 vr, vt;
            #pragma unroll
            for (int e = 0; e < 4; ++e) {
                f32x2 pr = *(const f32x2*)(orow + 2 * iv[e]);
                vr[e] = pr[0]; vt[e] = pr[1];
            }
            *(f32x4*)&out[(row0 + r) * NJ + jj]            = vr;
            *(f32x4*)&out[OUT_HALF + (row0 + r) * NJ + jj] = vt;
        }
        if (p == 0) __syncthreads();   // gather-0 done before pass-1 overwrites sO
    }
}

extern "C" void kernel_launch(void* const* d_in, const int* in_sizes, int n_in,
                              void* d_out, int out_size, void* d_ws, size_t ws_size,
                              hipStream_t stream) {
    const float* rgb  = (const float*)d_in[0];
    const float* tir  = (const float*)d_in[1];
    const int*   gidx = (const int*)d_in[2];
    const float* ln_g = (const float*)d_in[3];
    const float* ln_b = (const float*)d_in[4];
    const float* W1   = (const float*)d_in[5];
    const float* b1   = (const float*)d_in[6];
    const float* W2   = (const float*)d_in[7];
    const float* b2   = (const float*)d_in[8];
    float* out = (float*)d_out;
    short* wsp = (short*)d_ws;     // 512 KB: P1 at elem 0, P2 at elem 131072

    pack_weights<<<129, 256, 0, stream>>>(W1, W2, ln_g, ln_b, b1, wsp);
    fused_mlp<<<1024, 512, 0, stream>>>(rgb, tir, gidx,
                                        wsp, wsp + 131072, b2, out);
}